// Round 1
// baseline (1370.188 us; speedup 1.0000x reference)
//
#include <hip/hip_runtime.h>

typedef __bf16 bf16;
typedef __bf16 bf16x4 __attribute__((ext_vector_type(4)));
typedef __bf16 bf16x8 __attribute__((ext_vector_type(8)));
typedef float  f32x4  __attribute__((ext_vector_type(4)));

static constexpr int kC   = 1024;
static constexpr int kT   = 1024;
static constexpr int kB   = 4;
static constexpr int kH   = 16;
static constexpr int kHD  = 64;
static constexpr int kL   = 4;
static constexpr int kFF  = 100;
static constexpr int kFFP = 128;
static constexpr int kM   = kB * kT; // 4096 rows in the [B*T, C] view

// ---------------------------------------------------------------------------
// Transpose + fp32->bf16 convert:  dst[n][k] = src[k][n], dst dims NP x KP,
// zero-filled outside the src K x N range. Batched over blockIdx.z.
// ---------------------------------------------------------------------------
__global__ __launch_bounds__(256)
void trans_cvt(const float* __restrict__ src, long sStride,
               bf16* __restrict__ dst, long dStride,
               int K, int N, int KP, int NP)
{
    __shared__ float tile[32][33];
    const int z = blockIdx.z;
    src += (long)z * sStride;
    dst += (long)z * dStride;
    const int n0 = blockIdx.x * 32, k0 = blockIdx.y * 32;
    const int tx = threadIdx.x & 31, ty = threadIdx.x >> 5; // 32 x 8
#pragma unroll
    for (int i = 0; i < 4; ++i) {
        int k = k0 + ty + i * 8, n = n0 + tx;
        tile[ty + i * 8][tx] = (k < K && n < N) ? src[(long)k * N + n] : 0.f;
    }
    __syncthreads();
#pragma unroll
    for (int i = 0; i < 4; ++i) {
        int n = n0 + ty + i * 8, k = k0 + tx;
        if (n < NP && k < KP) dst[(long)n * KP + k] = (bf16)tile[tx][ty + i * 8];
    }
}

__global__ __launch_bounds__(256)
void pack_bias(const float* __restrict__ bq, const float* __restrict__ bk,
               const float* __restrict__ bv, float* __restrict__ dst)
{
    int gid = blockIdx.x * 256 + threadIdx.x; // < L*3*C = 12288
    int l = gid / (3 * kC), w = (gid / kC) % 3, c = gid & (kC - 1);
    const float* s = (w == 0) ? bq : (w == 1) ? bk : bv;
    dst[gid] = s[l * kC + c];
}

__global__ __launch_bounds__(256)
void zero_kernel(float* __restrict__ p, int n)
{
    int i = blockIdx.x * 256 + threadIdx.x;
    if (i < n) p[i] = 0.f;
}

// x[m][c] = tok_emb[idx[m]][c] + pos_emb[m % T][c]; one block per row m.
__global__ __launch_bounds__(256)
void embed_kernel(const int* __restrict__ idx, const float* __restrict__ tok,
                  const float* __restrict__ pos, float* __restrict__ x)
{
    const int m = blockIdx.x;
    const int c = threadIdx.x * 4;
    const int t = m & (kT - 1);
    const long tk = (long)idx[m] * kC;
    float4 a = *(const float4*)&tok[tk + c];
    float4 b = *(const float4*)&pos[(long)t * kC + c];
    float4 o; o.x = a.x + b.x; o.y = a.y + b.y; o.z = a.z + b.z; o.w = a.w + b.w;
    *(float4*)&x[(long)m * kC + c] = o;
}

// LayerNorm over rows of 1024; one block (256 thr) per row.
// outf32==0 -> write bf16 to ob ; outf32==1 -> write fp32 to of.
__global__ __launch_bounds__(256)
void ln_kernel(const float* __restrict__ x, const float* __restrict__ g,
               const float* __restrict__ be, bf16* __restrict__ ob,
               float* __restrict__ of, int outf32)
{
    __shared__ float red[8];
    const long row = blockIdx.x;
    const int tid = threadIdx.x, lane = tid & 63, wv = tid >> 6;
    const float4 v = *(const float4*)&x[row * kC + tid * 4];
    float s = v.x + v.y + v.z + v.w;
    float s2 = v.x * v.x + v.y * v.y + v.z * v.z + v.w * v.w;
#pragma unroll
    for (int o = 32; o > 0; o >>= 1) { s += __shfl_down(s, o); s2 += __shfl_down(s2, o); }
    if (!lane) { red[wv] = s; red[4 + wv] = s2; }
    __syncthreads();
    s  = red[0] + red[1] + red[2] + red[3];
    s2 = red[4] + red[5] + red[6] + red[7];
    const float mean = s * (1.f / kC);
    const float var  = s2 * (1.f / kC) - mean * mean;
    const float rstd = rsqrtf(var + 1e-5f);
    const float4 gg = *(const float4*)&g[tid * 4];
    const float4 bb = *(const float4*)&be[tid * 4];
    float o0 = (v.x - mean) * rstd * gg.x + bb.x;
    float o1 = (v.y - mean) * rstd * gg.y + bb.y;
    float o2 = (v.z - mean) * rstd * gg.z + bb.z;
    float o3 = (v.w - mean) * rstd * gg.w + bb.w;
    if (outf32) {
        float4 o; o.x = o0; o.y = o1; o.z = o2; o.w = o3;
        *(float4*)&of[row * kC + tid * 4] = o;
    } else {
        bf16x4 o; o[0] = (bf16)o0; o[1] = (bf16)o1; o[2] = (bf16)o2; o[3] = (bf16)o3;
        *(bf16x4*)&ob[row * kC + tid * 4] = o;
    }
}

// Row softmax over 1024 bf16, in place. One block per row.
__global__ __launch_bounds__(256)
void softmax_kernel(bf16* __restrict__ S)
{
    __shared__ float red[8];
    const long row = blockIdx.x;
    bf16* p = S + row * kT;
    const int tid = threadIdx.x, lane = tid & 63, wv = tid >> 6;
    bf16x4 tv = *(const bf16x4*)&p[tid * 4];
    float v0 = tv[0], v1 = tv[1], v2 = tv[2], v3 = tv[3];
    float m = fmaxf(fmaxf(v0, v1), fmaxf(v2, v3));
#pragma unroll
    for (int o = 32; o > 0; o >>= 1) m = fmaxf(m, __shfl_down(m, o));
    if (!lane) red[wv] = m;
    __syncthreads();
    m = fmaxf(fmaxf(red[0], red[1]), fmaxf(red[2], red[3]));
    float e0 = __expf(v0 - m), e1 = __expf(v1 - m), e2 = __expf(v2 - m), e3 = __expf(v3 - m);
    float s = e0 + e1 + e2 + e3;
#pragma unroll
    for (int o = 32; o > 0; o >>= 1) s += __shfl_down(s, o);
    if (!lane) red[4 + wv] = s;
    __syncthreads();
    s = red[4] + red[5] + red[6] + red[7];
    const float inv = 1.f / s;
    bf16x4 ov; ov[0] = (bf16)(e0 * inv); ov[1] = (bf16)(e1 * inv);
    ov[2] = (bf16)(e2 * inv); ov[3] = (bf16)(e3 * inv);
    *(bf16x4*)&p[tid * 4] = ov;
}

// ---------------------------------------------------------------------------
// MFMA GEMM:  C[M,N] = A[M,K] * B^T[N,K]   (B passed pre-transposed, k-contig)
// Block 256 thr = 4 waves (WAVES_M x WAVES_N), wave tile (AI*16) x (BJ*16).
// MODE 0: QKV combined  (z=0 q, z=1 k -> [B,H,T,HD]; z=2 v -> VT [B,H,HD,T])
// MODE 2: out bf16 = acc*scale, batched by z (QK^T scores)
// MODE 3: out bf16 = relu(acc + bias[gcol<kFF])          (FF1, N=kFFP)
// MODE 4: resid[grow*N+gcol] += acc + bias[gcol]         (O-proj, FF2)
// ---------------------------------------------------------------------------
template<int WAVES_M, int WAVES_N, int AI, int BJ, int MODE>
__global__ __launch_bounds__(256)
void gemm_bf16(const bf16* __restrict__ Ag, long strideA,
               const bf16* __restrict__ Bg, long strideB,
               const float* __restrict__ bias, int strideBias,
               bf16* __restrict__ outb, long strideOut,
               float* __restrict__ resid,
               int N, int K, int lda, int ldb, float scale)
{
    constexpr int BM = WAVES_M * AI * 16;
    constexpr int BN = WAVES_N * BJ * 16;
    constexpr int BK = 64;
    constexpr int LK = BK + 8; // pad: row stride 144 B -> ~2-way LDS banking
    __shared__ __align__(16) bf16 As[BM][LK];
    __shared__ __align__(16) bf16 Bs[BN][LK];
    const int tid = threadIdx.x, lane = tid & 63, wv = tid >> 6;
    const int wm = wv / WAVES_N, wn = wv % WAVES_N;
    const int lr = lane & 15, lg = lane >> 4;
    const int z = blockIdx.z;
    const bf16* A = Ag + (long)z * strideA;
    const bf16* B = Bg + (long)z * strideB;
    const float* bi = bias ? bias + (long)z * strideBias : nullptr;
    const int m0 = blockIdx.y * BM, n0 = blockIdx.x * BN;

    f32x4 acc[AI][BJ];
#pragma unroll
    for (int i = 0; i < AI; ++i)
#pragma unroll
        for (int j = 0; j < BJ; ++j) acc[i][j] = (f32x4){0.f, 0.f, 0.f, 0.f};

    for (int k0 = 0; k0 < K; k0 += BK) {
        constexpr int AP = (BM * BK) / (256 * 8);
#pragma unroll
        for (int p = 0; p < AP; ++p) {
            int r = p * 32 + (tid >> 3), c = (tid & 7) * 8;
            *(uint4*)&As[r][c] = *(const uint4*)&A[(long)(m0 + r) * lda + k0 + c];
        }
        constexpr int BP = (BN * BK) / (256 * 8);
#pragma unroll
        for (int p = 0; p < BP; ++p) {
            int r = p * 32 + (tid >> 3), c = (tid & 7) * 8;
            *(uint4*)&Bs[r][c] = *(const uint4*)&B[(long)(n0 + r) * ldb + k0 + c];
        }
        __syncthreads();
#pragma unroll
        for (int kk = 0; kk < 2; ++kk) {
            bf16x8 af[AI], bfv[BJ];
#pragma unroll
            for (int i = 0; i < AI; ++i)
                af[i] = *(const bf16x8*)&As[wm * AI * 16 + i * 16 + lr][kk * 32 + lg * 8];
#pragma unroll
            for (int j = 0; j < BJ; ++j)
                bfv[j] = *(const bf16x8*)&Bs[wn * BJ * 16 + j * 16 + lr][kk * 32 + lg * 8];
#pragma unroll
            for (int i = 0; i < AI; ++i)
#pragma unroll
                for (int j = 0; j < BJ; ++j)
                    acc[i][j] = __builtin_amdgcn_mfma_f32_16x16x32_bf16(af[i], bfv[j], acc[i][j], 0, 0, 0);
        }
        __syncthreads();
    }

#pragma unroll
    for (int i = 0; i < AI; ++i)
#pragma unroll
        for (int j = 0; j < BJ; ++j)
#pragma unroll
            for (int rr = 0; rr < 4; ++rr) {
                const int grow = m0 + wm * AI * 16 + i * 16 + lg * 4 + rr;
                const int gcol = n0 + wn * BJ * 16 + j * 16 + lr;
                float v = acc[i][j][rr];
                if constexpr (MODE == 0) {
                    v += bi[gcol];
                    const int b = grow >> 10, t = grow & (kT - 1);
                    const int hh = gcol >> 6, hd = gcol & 63;
                    long o = (long)z * strideOut;
                    if (z == 2) o += (((long)b * kH + hh) * kHD + hd) * kT + t;  // VT
                    else        o += (((long)b * kH + hh) * kT + t) * kHD + hd;  // Q/K
                    outb[o] = (bf16)v;
                } else if constexpr (MODE == 2) {
                    outb[(long)z * strideOut + (long)grow * N + gcol] = (bf16)(v * scale);
                } else if constexpr (MODE == 3) {
                    v += (gcol < kFF) ? bi[gcol] : 0.f;
                    outb[(long)grow * N + gcol] = (bf16)fmaxf(v, 0.f);
                } else {
                    v += bi[gcol];
                    resid[(long)grow * N + gcol] += v;
                }
            }
}

// ---------------------------------------------------------------------------
// PV + att-mean:  y[b,q,h*64+hd] = sum_t P[b,h,q,t] * V[b,h,t,hd]
// and att_maps[h,q,t] = mean_b P. Block = (qt, h), loops b and k-tiles.
// ---------------------------------------------------------------------------
__global__ __launch_bounds__(256)
void pv_kernel(const bf16* __restrict__ P, const bf16* __restrict__ VT,
               bf16* __restrict__ y, float* __restrict__ attm)
{
    constexpr int KB = 32, LK = KB + 8;
    __shared__ __align__(16) bf16 Ps[4][64][LK];
    __shared__ __align__(16) bf16 Vs[4][64][LK];
    const int qt = blockIdx.x, h = blockIdx.y;
    const int tid = threadIdx.x, lane = tid & 63, wv = tid >> 6;
    const int lr = lane & 15, lg = lane >> 4;
    const int r = tid >> 2, c = (tid & 3) * 8; // 64 rows x 4 chunks of 8

    f32x4 acc[4][4];
#pragma unroll
    for (int b = 0; b < 4; ++b)
#pragma unroll
        for (int j = 0; j < 4; ++j) acc[b][j] = (f32x4){0.f, 0.f, 0.f, 0.f};

    for (int kt = 0; kt < kT / KB; ++kt) {
#pragma unroll
        for (int b = 0; b < 4; ++b) {
            const long bh = (long)b * kH + h;
            *(uint4*)&Ps[b][r][c] = *(const uint4*)&P[(bh * kT + qt * 64 + r) * kT + kt * KB + c];
            *(uint4*)&Vs[b][r][c] = *(const uint4*)&VT[(bh * kHD + r) * kT + kt * KB + c];
        }
        __syncthreads();
        // att mean over batch for this (64 x KB) tile
        {
            float* dst = attm + ((long)h * kT + qt * 64 + r) * kT + kt * KB + c;
#pragma unroll
            for (int e = 0; e < 8; ++e) {
                float t0 = (float)Ps[0][r][c + e] + (float)Ps[1][r][c + e]
                         + (float)Ps[2][r][c + e] + (float)Ps[3][r][c + e];
                dst[e] = t0 * 0.25f;
            }
        }
#pragma unroll
        for (int b = 0; b < 4; ++b) {
            bf16x8 a = *(const bf16x8*)&Ps[b][wv * 16 + lr][lg * 8];
#pragma unroll
            for (int j = 0; j < 4; ++j) {
                bf16x8 bv = *(const bf16x8*)&Vs[b][j * 16 + lr][lg * 8];
                acc[b][j] = __builtin_amdgcn_mfma_f32_16x16x32_bf16(a, bv, acc[b][j], 0, 0, 0);
            }
        }
        __syncthreads();
    }
#pragma unroll
    for (int b = 0; b < 4; ++b)
#pragma unroll
        for (int j = 0; j < 4; ++j)
#pragma unroll
            for (int rr = 0; rr < 4; ++rr) {
                const int row = qt * 64 + wv * 16 + lg * 4 + rr;
                const int col = h * kHD + j * 16 + lr;
                y[((long)b * kT + row) * kC + col] = (bf16)acc[b][j][rr];
            }
}

// pooled[b][c] = mean_t xf[b,t,c]; partial over t-chunks via atomicAdd.
__global__ __launch_bounds__(256)
void pool_kernel(const float* __restrict__ xf, float* __restrict__ pooled)
{
    const int c = blockIdx.x * 256 + threadIdx.x;
    const int b = blockIdx.y;
    const int t0 = blockIdx.z * 128;
    float s = 0.f;
    for (int t = t0; t < t0 + 128; ++t) s += xf[((long)b * kT + t) * kC + c];
    atomicAdd(&pooled[b * kC + c], s * (1.f / kT));
}

// ---------------------------------------------------------------------------
extern "C" void kernel_launch(void* const* d_in, const int* in_sizes, int n_in,
                              void* d_out, int out_size, void* d_ws, size_t ws_size,
                              hipStream_t stream)
{
    const int*   idx  = (const int*)d_in[0];
    const float* tok  = (const float*)d_in[1];
    const float* pos  = (const float*)d_in[2];
    const float* Wq   = (const float*)d_in[3];
    const float* bq   = (const float*)d_in[4];
    const float* Wk   = (const float*)d_in[5];
    const float* bk   = (const float*)d_in[6];
    const float* Wv   = (const float*)d_in[7];
    const float* bv   = (const float*)d_in[8];
    const float* Wo   = (const float*)d_in[9];
    const float* bo   = (const float*)d_in[10];
    const float* ln1w = (const float*)d_in[11];
    const float* ln1b = (const float*)d_in[12];
    const float* ln2w = (const float*)d_in[13];
    const float* ln2b = (const float*)d_in[14];
    const float* W1   = (const float*)d_in[15];
    const float* b1   = (const float*)d_in[16];
    const float* W2   = (const float*)d_in[17];
    const float* b2   = (const float*)d_in[18];
    const float* lnfw = (const float*)d_in[19];
    const float* lnfb = (const float*)d_in[20];

    char* ws = (char*)d_ws;
    long off = 0;
    auto alloc = [&](long bytes) { char* p = ws + off; off += (bytes + 255) & ~255L; return p; };
    bf16*  WQKVT = (bf16*)alloc((long)kL * 3 * kC * kC * 2);
    bf16*  WOT   = (bf16*)alloc((long)kL * kC * kC * 2);
    bf16*  W1T   = (bf16*)alloc((long)kL * kFFP * kC * 2);
    bf16*  W2T   = (bf16*)alloc((long)kL * kC * kFFP * 2);
    float* BQKV  = (float*)alloc((long)kL * 3 * kC * 4);
    float* X     = (float*)alloc((long)kM * kC * 4);
    bf16*  Hbuf  = (bf16*)alloc((long)kM * kC * 2);
    bf16*  QKV   = (bf16*)alloc(3L * kM * kC * 2);
    bf16*  Y     = (bf16*)alloc((long)kM * kC * 2);
    bf16*  F1    = (bf16*)alloc((long)kM * kFFP * 2);
    bf16*  S     = (bf16*)alloc((long)kB * kH * kT * kT * 2);
    float* XF    = (float*)S; // final-LN output reuses the scores buffer

    float* pooled = (float*)d_out;
    float* attm_base = pooled + kB * kC;

    // ---- prep: zero pooled, pack weights (bf16, transposed), pack biases
    zero_kernel<<<16, 256, 0, stream>>>(pooled, kB * kC);
    dim3 tg(32, 32, kL);
    trans_cvt<<<tg, 256, 0, stream>>>(Wq, (long)kC * kC, WQKVT + 0L * kC * kC, 3L * kC * kC, kC, kC, kC, kC);
    trans_cvt<<<tg, 256, 0, stream>>>(Wk, (long)kC * kC, WQKVT + 1L * kC * kC, 3L * kC * kC, kC, kC, kC, kC);
    trans_cvt<<<tg, 256, 0, stream>>>(Wv, (long)kC * kC, WQKVT + 2L * kC * kC, 3L * kC * kC, kC, kC, kC, kC);
    trans_cvt<<<tg, 256, 0, stream>>>(Wo, (long)kC * kC, WOT, (long)kC * kC, kC, kC, kC, kC);
    trans_cvt<<<dim3(4, 32, kL), 256, 0, stream>>>(W1, (long)kC * kFF, W1T, (long)kFFP * kC, kC, kFF, kC, kFFP);
    trans_cvt<<<dim3(32, 4, kL), 256, 0, stream>>>(W2, (long)kFF * kC, W2T, (long)kC * kFFP, kFF, kC, kFFP, kC);
    pack_bias<<<48, 256, 0, stream>>>(bq, bk, bv, BQKV);

    embed_kernel<<<kM, 256, 0, stream>>>(idx, tok, pos, X);

    const float scale = 0.125f; // 1/sqrt(64)
    for (int l = 0; l < kL; ++l) {
        ln_kernel<<<kM, 256, 0, stream>>>(X, ln1w + l * kC, ln1b + l * kC, Hbuf, nullptr, 0);
        // QKV: one launch, z in {q,k,v}
        gemm_bf16<2, 2, 4, 4, 0><<<dim3(8, 32, 3), 256, 0, stream>>>(
            Hbuf, 0L, WQKVT + (long)l * 3 * kC * kC, (long)kC * kC,
            BQKV + l * 3 * kC, kC, QKV, (long)kM * kC, nullptr,
            kC, kC, kC, kC, 1.f);
        // S = Q K^T * scale, batched over (b,h)
        gemm_bf16<2, 2, 4, 4, 2><<<dim3(8, 8, kB * kH), 256, 0, stream>>>(
            QKV, (long)kT * kHD, QKV + (long)kM * kC, (long)kT * kHD,
            nullptr, 0, S, (long)kT * kT, nullptr,
            kT, kHD, kHD, kHD, scale);
        softmax_kernel<<<kB * kH * kT, 256, 0, stream>>>(S);
        pv_kernel<<<dim3(16, 16), 256, 0, stream>>>(S, QKV + 2L * kM * kC, Y,
                                                    attm_base + (long)l * kH * kT * kT);
        // x += y @ Wo + bo
        gemm_bf16<2, 2, 4, 4, 4><<<dim3(8, 32, 1), 256, 0, stream>>>(
            Y, 0L, WOT + (long)l * kC * kC, 0L, bo + l * kC, 0,
            nullptr, 0L, X, kC, kC, kC, kC, 1.f);
        ln_kernel<<<kM, 256, 0, stream>>>(X, ln2w + l * kC, ln2b + l * kC, Hbuf, nullptr, 0);
        // f1 = relu(h @ W1 + b1), N padded to 128
        gemm_bf16<2, 2, 1, 4, 3><<<dim3(1, 128, 1), 256, 0, stream>>>(
            Hbuf, 0L, W1T + (long)l * kFFP * kC, 0L, b1 + l * kFF, 0,
            F1, 0L, nullptr, kFFP, kC, kC, kC, 1.f);
        // x += f1 @ W2 + b2  (K padded to 128, pad cols of f1 are zero)
        gemm_bf16<2, 2, 4, 4, 4><<<dim3(8, 32, 1), 256, 0, stream>>>(
            F1, 0L, W2T + (long)l * kC * kFFP, 0L, b2 + l * kC, 0,
            nullptr, 0L, X, kC, kFFP, kFFP, kFFP, 1.f);
    }
    ln_kernel<<<kM, 256, 0, stream>>>(X, lnfw, lnfb, nullptr, XF, 1);
    pool_kernel<<<dim3(4, kB, 8), 256, 0, stream>>>(XF, pooled);
}

// Round 2
// 1127.384 us; speedup vs baseline: 1.2154x; 1.2154x over previous
//
#include <hip/hip_runtime.h>

typedef __bf16 bf16;
typedef __bf16 bf16x4 __attribute__((ext_vector_type(4)));
typedef __bf16 bf16x8 __attribute__((ext_vector_type(8)));
typedef float  f32x4  __attribute__((ext_vector_type(4)));

static constexpr int kC   = 1024;
static constexpr int kT   = 1024;
static constexpr int kB   = 4;
static constexpr int kH   = 16;
static constexpr int kHD  = 64;
static constexpr int kL   = 4;
static constexpr int kFF  = 100;
static constexpr int kFFP = 128;
static constexpr int kM   = kB * kT;

// async global->LDS, 16B per lane; LDS dest must be wave-uniform (HW adds lane*16)
__device__ __forceinline__ void gload16(const bf16* g, bf16* l)
{
    __builtin_amdgcn_global_load_lds(
        (const __attribute__((address_space(1))) void*)g,
        (__attribute__((address_space(3))) void*)l, 16, 0, 0);
}

// ---------------------------------------------------------------------------
__global__ __launch_bounds__(256)
void trans_cvt(const float* __restrict__ src, long sStride,
               bf16* __restrict__ dst, long dStride,
               int K, int N, int KP, int NP)
{
    __shared__ float tile[32][33];
    const int z = blockIdx.z;
    src += (long)z * sStride;
    dst += (long)z * dStride;
    const int n0 = blockIdx.x * 32, k0 = blockIdx.y * 32;
    const int tx = threadIdx.x & 31, ty = threadIdx.x >> 5;
#pragma unroll
    for (int i = 0; i < 4; ++i) {
        int k = k0 + ty + i * 8, n = n0 + tx;
        tile[ty + i * 8][tx] = (k < K && n < N) ? src[(long)k * N + n] : 0.f;
    }
    __syncthreads();
#pragma unroll
    for (int i = 0; i < 4; ++i) {
        int n = n0 + ty + i * 8, k = k0 + tx;
        if (n < NP && k < KP) dst[(long)n * KP + k] = (bf16)tile[tx][ty + i * 8];
    }
}

__global__ __launch_bounds__(256)
void pack_bias(const float* __restrict__ bq, const float* __restrict__ bk,
               const float* __restrict__ bv, float* __restrict__ dst)
{
    int gid = blockIdx.x * 256 + threadIdx.x;
    int l = gid / (3 * kC), w = (gid / kC) % 3, c = gid & (kC - 1);
    const float* s = (w == 0) ? bq : (w == 1) ? bk : bv;
    dst[gid] = s[l * kC + c];
}

__global__ __launch_bounds__(256)
void zero_kernel(float* __restrict__ p, int n)
{
    int i = blockIdx.x * 256 + threadIdx.x;
    if (i < n) p[i] = 0.f;
}

__global__ __launch_bounds__(256)
void embed_kernel(const int* __restrict__ idx, const float* __restrict__ tok,
                  const float* __restrict__ pos, float* __restrict__ x)
{
    const int m = blockIdx.x;
    const int c = threadIdx.x * 4;
    const int t = m & (kT - 1);
    const long tk = (long)idx[m] * kC;
    float4 a = *(const float4*)&tok[tk + c];
    float4 b = *(const float4*)&pos[(long)t * kC + c];
    float4 o; o.x = a.x + b.x; o.y = a.y + b.y; o.z = a.z + b.z; o.w = a.w + b.w;
    *(float4*)&x[(long)m * kC + c] = o;
}

__global__ __launch_bounds__(256)
void ln_kernel(const float* __restrict__ x, const float* __restrict__ g,
               const float* __restrict__ be, bf16* __restrict__ ob,
               float* __restrict__ of, int outf32)
{
    __shared__ float red[8];
    const long row = blockIdx.x;
    const int tid = threadIdx.x, lane = tid & 63, wv = tid >> 6;
    const float4 v = *(const float4*)&x[row * kC + tid * 4];
    float s = v.x + v.y + v.z + v.w;
    float s2 = v.x * v.x + v.y * v.y + v.z * v.z + v.w * v.w;
#pragma unroll
    for (int o = 32; o > 0; o >>= 1) { s += __shfl_down(s, o); s2 += __shfl_down(s2, o); }
    if (!lane) { red[wv] = s; red[4 + wv] = s2; }
    __syncthreads();
    s  = red[0] + red[1] + red[2] + red[3];
    s2 = red[4] + red[5] + red[6] + red[7];
    const float mean = s * (1.f / kC);
    const float var  = s2 * (1.f / kC) - mean * mean;
    const float rstd = rsqrtf(var + 1e-5f);
    const float4 gg = *(const float4*)&g[tid * 4];
    const float4 bb = *(const float4*)&be[tid * 4];
    float o0 = (v.x - mean) * rstd * gg.x + bb.x;
    float o1 = (v.y - mean) * rstd * gg.y + bb.y;
    float o2 = (v.z - mean) * rstd * gg.z + bb.z;
    float o3 = (v.w - mean) * rstd * gg.w + bb.w;
    if (outf32) {
        float4 o; o.x = o0; o.y = o1; o.z = o2; o.w = o3;
        *(float4*)&of[row * kC + tid * 4] = o;
    } else {
        bf16x4 o; o[0] = (bf16)o0; o[1] = (bf16)o1; o[2] = (bf16)o2; o[3] = (bf16)o3;
        *(bf16x4*)&ob[row * kC + tid * 4] = o;
    }
}

// ---------------------------------------------------------------------------
// MFMA GEMM: C[M,N] = A[M,K] * B^T[N,K]. GL=1: global_load_lds staging with
// 16B-block XOR swizzle (128x128 tile only). GL=0: reg-staged, padded LDS.
// MODE 0: QKV (z=0 q, z=1 k -> [B,H,T,HD]; z=2 v -> VT [B,H,HD,T])
// MODE 3: out bf16 = relu(acc + bias[gcol<kFF])
// MODE 4: resid[grow*N+gcol] += acc + bias[gcol]
// ---------------------------------------------------------------------------
template<int WAVES_M, int WAVES_N, int AI, int BJ, int MODE, int GL>
__global__ __launch_bounds__(256)
void gemm_bf16(const bf16* __restrict__ Ag, long strideA,
               const bf16* __restrict__ Bg, long strideB,
               const float* __restrict__ bias, int strideBias,
               bf16* __restrict__ outb, long strideOut,
               float* __restrict__ resid,
               int N, int K, int lda, int ldb)
{
    constexpr int BM = WAVES_M * AI * 16;
    constexpr int BN = WAVES_N * BJ * 16;
    constexpr int BK = 64;
    constexpr int LK = GL ? BK : (BK + 8);
    __shared__ __align__(16) bf16 As[BM * LK];
    __shared__ __align__(16) bf16 Bs[BN * LK];
    const int tid = threadIdx.x, lane = tid & 63, wv = tid >> 6;
    const int wm = wv / WAVES_N, wn = wv % WAVES_N;
    const int lr = lane & 15, lg = lane >> 4;
    const int z = blockIdx.z;
    const bf16* A = Ag + (long)z * strideA;
    const bf16* B = Bg + (long)z * strideB;
    const float* bi = bias ? bias + (long)z * strideBias : nullptr;
    const int m0 = blockIdx.y * BM, n0 = blockIdx.x * BN;

    f32x4 acc[AI][BJ];
#pragma unroll
    for (int i = 0; i < AI; ++i)
#pragma unroll
        for (int j = 0; j < BJ; ++j) acc[i][j] = (f32x4){0.f, 0.f, 0.f, 0.f};

    for (int k0 = 0; k0 < K; k0 += BK) {
        if constexpr (GL) {
            static_assert(BM == 128 && BN == 128, "GL path needs 128x128 tile");
            const int srow = wv * 32 + (lane >> 3);          // row this lane stages
            const int gcb  = (lane & 7) ^ (lane >> 3);       // inverse-swizzled src col
#pragma unroll
            for (int p = 0; p < 4; ++p) {
                gload16(A + (long)(m0 + srow + p * 8) * lda + k0 + gcb * 8,
                        &As[(wv * 32 + p * 8) * BK]);
                gload16(B + (long)(n0 + srow + p * 8) * ldb + k0 + gcb * 8,
                        &Bs[(wv * 32 + p * 8) * BK]);
            }
        } else {
            constexpr int AP = (BM * BK) / (256 * 8);
#pragma unroll
            for (int p = 0; p < AP; ++p) {
                int r = p * 32 + (tid >> 3), c = (tid & 7) * 8;
                *(uint4*)&As[r * LK + c] = *(const uint4*)&A[(long)(m0 + r) * lda + k0 + c];
            }
            constexpr int BP = (BN * BK) / (256 * 8);
#pragma unroll
            for (int p = 0; p < BP; ++p) {
                int r = p * 32 + (tid >> 3), c = (tid & 7) * 8;
                *(uint4*)&Bs[r * LK + c] = *(const uint4*)&B[(long)(n0 + r) * ldb + k0 + c];
            }
        }
        __syncthreads();
#pragma unroll
        for (int kk = 0; kk < 2; ++kk) {
            bf16x8 af[AI], bfv[BJ];
#pragma unroll
            for (int i = 0; i < AI; ++i) {
                const int r = wm * AI * 16 + i * 16 + lr;
                const int c = GL ? (((kk * 4 + lg) ^ (lr & 7)) * 8) : (kk * 32 + lg * 8);
                af[i] = *(const bf16x8*)&As[r * LK + c];
            }
#pragma unroll
            for (int j = 0; j < BJ; ++j) {
                const int r = wn * BJ * 16 + j * 16 + lr;
                const int c = GL ? (((kk * 4 + lg) ^ (lr & 7)) * 8) : (kk * 32 + lg * 8);
                bfv[j] = *(const bf16x8*)&Bs[r * LK + c];
            }
#pragma unroll
            for (int i = 0; i < AI; ++i)
#pragma unroll
                for (int j = 0; j < BJ; ++j)
                    acc[i][j] = __builtin_amdgcn_mfma_f32_16x16x32_bf16(af[i], bfv[j], acc[i][j], 0, 0, 0);
        }
        __syncthreads();
    }

#pragma unroll
    for (int i = 0; i < AI; ++i)
#pragma unroll
        for (int j = 0; j < BJ; ++j)
#pragma unroll
            for (int rr = 0; rr < 4; ++rr) {
                const int grow = m0 + wm * AI * 16 + i * 16 + lg * 4 + rr;
                const int gcol = n0 + wn * BJ * 16 + j * 16 + lr;
                float v = acc[i][j][rr];
                if constexpr (MODE == 0) {
                    v += bi[gcol];
                    const int b = grow >> 10, t = grow & (kT - 1);
                    const int hh = gcol >> 6, hd = gcol & 63;
                    long o = (long)z * strideOut;
                    if (z == 2) o += (((long)b * kH + hh) * kHD + hd) * kT + t;  // VT
                    else        o += (((long)b * kH + hh) * kT + t) * kHD + hd;  // Q/K
                    outb[o] = (bf16)v;
                } else if constexpr (MODE == 3) {
                    v += (gcol < kFF) ? bi[gcol] : 0.f;
                    outb[(long)grow * N + gcol] = (bf16)fmaxf(v, 0.f);
                } else {
                    v += bi[gcol];
                    resid[(long)grow * N + gcol] += v;
                }
            }
}

// ---------------------------------------------------------------------------
// Fused QK^T + softmax:  P[bh][q][t] = softmax_t(Q[bh][q][:] . K[bh][t][:] / 8)
// Block = (32 q-rows, bh), 8 waves; wave w owns cols w*128..w*128+127.
// Full K[bh] (1024x64, 128 KB) staged in LDS, XOR-swizzled 16B blocks.
// ---------------------------------------------------------------------------
__global__ __launch_bounds__(512)
void attn_score(const bf16* __restrict__ Qg, const bf16* __restrict__ Kg,
                bf16* __restrict__ Pg)
{
    __shared__ __align__(16) bf16 Ks[kT * kHD];   // 128 KB
    __shared__ __align__(16) bf16 Qs[32 * kHD];   // 4 KB
    __shared__ float redm[32][8];
    __shared__ float reds[32][8];
    const int tid = threadIdx.x, lane = tid & 63, w = tid >> 6;
    const int lr = lane & 15, lg = lane >> 4;
    const long bh = blockIdx.y;
    const int q0 = blockIdx.x * 32;
    const bf16* Qb = Qg + (bh * kT + q0) * kHD;
    const bf16* Kb = Kg + bh * kT * kHD;

    const int srow8 = lane >> 3;                 // row within 8-row chunk
    const int gcb   = (lane & 7) ^ srow8;        // inverse-swizzled source col block
#pragma unroll
    for (int p = 0; p < 16; ++p) {
        const int r0 = w * 128 + p * 8;
        gload16(Kb + (long)(r0 + srow8) * kHD + gcb * 8, &Ks[r0 * kHD]);
    }
    if (w < 4)
        gload16(Qb + (long)(w * 8 + srow8) * kHD + gcb * 8, &Qs[w * 8 * kHD]);
    __syncthreads();

    bf16x8 af[2][2];
#pragma unroll
    for (int i = 0; i < 2; ++i)
#pragma unroll
        for (int kk = 0; kk < 2; ++kk)
            af[i][kk] = *(const bf16x8*)&Qs[(i * 16 + lr) * kHD + (((kk * 4 + lg) ^ (lr & 7)) * 8)];

    f32x4 acc[2][8];
#pragma unroll
    for (int i = 0; i < 2; ++i)
#pragma unroll
        for (int j = 0; j < 8; ++j) acc[i][j] = (f32x4){0.f, 0.f, 0.f, 0.f};

#pragma unroll
    for (int j = 0; j < 8; ++j) {
        const int n = w * 128 + j * 16 + lr;
#pragma unroll
        for (int kk = 0; kk < 2; ++kk) {
            bf16x8 bf = *(const bf16x8*)&Ks[n * kHD + (((kk * 4 + lg) ^ (lr & 7)) * 8)];
            acc[0][j] = __builtin_amdgcn_mfma_f32_16x16x32_bf16(af[0][kk], bf, acc[0][j], 0, 0, 0);
            acc[1][j] = __builtin_amdgcn_mfma_f32_16x16x32_bf16(af[1][kk], bf, acc[1][j], 0, 0, 0);
        }
    }

    // per-row max over this wave's 128 cols, then cross-wave via LDS
    float mx[2][4];
#pragma unroll
    for (int i = 0; i < 2; ++i)
#pragma unroll
        for (int rr = 0; rr < 4; ++rr) {
            float m = acc[i][0][rr];
#pragma unroll
            for (int j = 1; j < 8; ++j) m = fmaxf(m, acc[i][j][rr]);
#pragma unroll
            for (int off = 1; off < 16; off <<= 1) m = fmaxf(m, __shfl_xor(m, off));
            mx[i][rr] = m;
            if (lr == 0) redm[i * 16 + lg * 4 + rr][w] = m;
        }
    __syncthreads();
    float fm[2][4];
#pragma unroll
    for (int i = 0; i < 2; ++i)
#pragma unroll
        for (int rr = 0; rr < 4; ++rr) {
            const int row = i * 16 + lg * 4 + rr;
            float4 a = *(const float4*)&redm[row][0];
            float4 b = *(const float4*)&redm[row][4];
            fm[i][rr] = fmaxf(fmaxf(fmaxf(a.x, a.y), fmaxf(a.z, a.w)),
                              fmaxf(fmaxf(b.x, b.y), fmaxf(b.z, b.w)));
        }

    constexpr float scale = 0.125f; // 1/sqrt(64)
    float sum[2][4];
#pragma unroll
    for (int i = 0; i < 2; ++i)
#pragma unroll
        for (int rr = 0; rr < 4; ++rr) {
            float s = 0.f;
#pragma unroll
            for (int j = 0; j < 8; ++j) {
                float e = __expf((acc[i][j][rr] - fm[i][rr]) * scale);
                acc[i][j][rr] = e;
                s += e;
            }
#pragma unroll
            for (int off = 1; off < 16; off <<= 1) s += __shfl_xor(s, off);
            sum[i][rr] = s;
            if (lr == 0) reds[i * 16 + lg * 4 + rr][w] = s;
        }
    __syncthreads();

    bf16* Pp = Pg + (bh * kT + q0) * kT;
#pragma unroll
    for (int i = 0; i < 2; ++i)
#pragma unroll
        for (int rr = 0; rr < 4; ++rr) {
            const int row = i * 16 + lg * 4 + rr;
            float4 a = *(const float4*)&reds[row][0];
            float4 b = *(const float4*)&reds[row][4];
            const float tot = (a.x + a.y + a.z + a.w) + (b.x + b.y + b.z + b.w);
            const float inv = 1.f / tot;
#pragma unroll
            for (int j = 0; j < 8; ++j)
                Pp[(long)row * kT + w * 128 + j * 16 + lr] = (bf16)(acc[i][j][rr] * inv);
        }
}

// ---------------------------------------------------------------------------
// PV + att-mean. Block = (64 q-rows, h), 512 thr = 8 waves; wave = (b, rowhalf).
// ---------------------------------------------------------------------------
__global__ __launch_bounds__(512)
void pv_kernel(const bf16* __restrict__ P, const bf16* __restrict__ VT,
               bf16* __restrict__ y, float* __restrict__ attm)
{
    constexpr int KB = 32, LP = KB + 8;
    __shared__ __align__(16) bf16 Ps[4][64][LP];
    __shared__ __align__(16) bf16 Vs[4][64][LP];
    const int qt = blockIdx.x, h = blockIdx.y;
    const int tid = threadIdx.x, lane = tid & 63, w = tid >> 6;
    const int b = w >> 1, rh = w & 1;
    const int lr = lane & 15, lg = lane >> 4;

    f32x4 acc[2][4];
#pragma unroll
    for (int i = 0; i < 2; ++i)
#pragma unroll
        for (int j = 0; j < 4; ++j) acc[i][j] = (f32x4){0.f, 0.f, 0.f, 0.f};

    for (int kt = 0; kt < kT / KB; ++kt) {
#pragma unroll
        for (int pass = 0; pass < 2; ++pass) {
            const int Lf = pass * 512 + tid;
            const int bb = Lf >> 8, r = (Lf >> 2) & 63, cb = Lf & 3;
            const long bhs = (long)bb * kH + h;
            *(uint4*)&Ps[bb][r][cb * 8] =
                *(const uint4*)&P[(bhs * kT + qt * 64 + r) * kT + kt * KB + cb * 8];
            *(uint4*)&Vs[bb][r][cb * 8] =
                *(const uint4*)&VT[(bhs * kHD + r) * kT + kt * KB + cb * 8];
        }
        __syncthreads();
        // att mean over batch (vectorized fp32 write)
        {
            const int r = tid >> 3, c4 = (tid & 7) * 4;
            float4 o;
#pragma unroll
            for (int e = 0; e < 4; ++e) {
                float t0 = (float)Ps[0][r][c4 + e] + (float)Ps[1][r][c4 + e]
                         + (float)Ps[2][r][c4 + e] + (float)Ps[3][r][c4 + e];
                ((float*)&o)[e] = t0 * 0.25f;
            }
            *(float4*)&attm[((long)h * kT + qt * 64 + r) * kT + kt * KB + c4] = o;
        }
        bf16x8 a[2];
#pragma unroll
        for (int i = 0; i < 2; ++i)
            a[i] = *(const bf16x8*)&Ps[b][rh * 32 + i * 16 + lr][lg * 8];
#pragma unroll
        for (int j = 0; j < 4; ++j) {
            bf16x8 bv = *(const bf16x8*)&Vs[b][j * 16 + lr][lg * 8];
#pragma unroll
            for (int i = 0; i < 2; ++i)
                acc[i][j] = __builtin_amdgcn_mfma_f32_16x16x32_bf16(a[i], bv, acc[i][j], 0, 0, 0);
        }
        __syncthreads();
    }
#pragma unroll
    for (int i = 0; i < 2; ++i)
#pragma unroll
        for (int j = 0; j < 4; ++j)
#pragma unroll
            for (int rr = 0; rr < 4; ++rr) {
                const int row = qt * 64 + rh * 32 + i * 16 + lg * 4 + rr;
                const int col = h * kHD + j * 16 + lr;
                y[((long)b * kT + row) * kC + col] = (bf16)acc[i][j][rr];
            }
}

__global__ __launch_bounds__(256)
void pool_kernel(const float* __restrict__ xf, float* __restrict__ pooled)
{
    const int c = blockIdx.x * 256 + threadIdx.x;
    const int b = blockIdx.y;
    const int t0 = blockIdx.z * 128;
    float s = 0.f;
    for (int t = t0; t < t0 + 128; ++t) s += xf[((long)b * kT + t) * kC + c];
    atomicAdd(&pooled[b * kC + c], s * (1.f / kT));
}

// ---------------------------------------------------------------------------
extern "C" void kernel_launch(void* const* d_in, const int* in_sizes, int n_in,
                              void* d_out, int out_size, void* d_ws, size_t ws_size,
                              hipStream_t stream)
{
    const int*   idx  = (const int*)d_in[0];
    const float* tok  = (const float*)d_in[1];
    const float* pos  = (const float*)d_in[2];
    const float* Wq   = (const float*)d_in[3];
    const float* bq   = (const float*)d_in[4];
    const float* Wk   = (const float*)d_in[5];
    const float* bk   = (const float*)d_in[6];
    const float* Wv   = (const float*)d_in[7];
    const float* bv   = (const float*)d_in[8];
    const float* Wo   = (const float*)d_in[9];
    const float* bo   = (const float*)d_in[10];
    const float* ln1w = (const float*)d_in[11];
    const float* ln1b = (const float*)d_in[12];
    const float* ln2w = (const float*)d_in[13];
    const float* ln2b = (const float*)d_in[14];
    const float* W1   = (const float*)d_in[15];
    const float* b1   = (const float*)d_in[16];
    const float* W2   = (const float*)d_in[17];
    const float* b2   = (const float*)d_in[18];
    const float* lnfw = (const float*)d_in[19];
    const float* lnfb = (const float*)d_in[20];

    char* ws = (char*)d_ws;
    long off = 0;
    auto alloc = [&](long bytes) { char* p = ws + off; off += (bytes + 255) & ~255L; return p; };
    bf16*  WQKVT = (bf16*)alloc((long)kL * 3 * kC * kC * 2);
    bf16*  WOT   = (bf16*)alloc((long)kL * kC * kC * 2);
    bf16*  W1T   = (bf16*)alloc((long)kL * kFFP * kC * 2);
    bf16*  W2T   = (bf16*)alloc((long)kL * kC * kFFP * 2);
    float* BQKV  = (float*)alloc((long)kL * 3 * kC * 4);
    float* X     = (float*)alloc((long)kM * kC * 4);
    bf16*  Hbuf  = (bf16*)alloc((long)kM * kC * 2);
    bf16*  QKV   = (bf16*)alloc(3L * kM * kC * 2);
    bf16*  Y     = (bf16*)alloc((long)kM * kC * 2);
    bf16*  F1    = (bf16*)alloc((long)kM * kFFP * 2);
    bf16*  S     = (bf16*)alloc((long)kB * kH * kT * kT * 2);
    float* XF    = (float*)S;

    float* pooled = (float*)d_out;
    float* attm_base = pooled + kB * kC;

    zero_kernel<<<16, 256, 0, stream>>>(pooled, kB * kC);
    dim3 tg(32, 32, kL);
    trans_cvt<<<tg, 256, 0, stream>>>(Wq, (long)kC * kC, WQKVT + 0L * kC * kC, 3L * kC * kC, kC, kC, kC, kC);
    trans_cvt<<<tg, 256, 0, stream>>>(Wk, (long)kC * kC, WQKVT + 1L * kC * kC, 3L * kC * kC, kC, kC, kC, kC);
    trans_cvt<<<tg, 256, 0, stream>>>(Wv, (long)kC * kC, WQKVT + 2L * kC * kC, 3L * kC * kC, kC, kC, kC, kC);
    trans_cvt<<<tg, 256, 0, stream>>>(Wo, (long)kC * kC, WOT, (long)kC * kC, kC, kC, kC, kC);
    trans_cvt<<<dim3(4, 32, kL), 256, 0, stream>>>(W1, (long)kC * kFF, W1T, (long)kFFP * kC, kC, kFF, kC, kFFP);
    trans_cvt<<<dim3(32, 4, kL), 256, 0, stream>>>(W2, (long)kFF * kC, W2T, (long)kC * kFFP, kFF, kC, kFFP, kC);
    pack_bias<<<48, 256, 0, stream>>>(bq, bk, bv, BQKV);

    embed_kernel<<<kM, 256, 0, stream>>>(idx, tok, pos, X);

    for (int l = 0; l < kL; ++l) {
        ln_kernel<<<kM, 256, 0, stream>>>(X, ln1w + l * kC, ln1b + l * kC, Hbuf, nullptr, 0);
        gemm_bf16<2, 2, 4, 4, 0, 1><<<dim3(8, 32, 3), 256, 0, stream>>>(
            Hbuf, 0L, WQKVT + (long)l * 3 * kC * kC, (long)kC * kC,
            BQKV + l * 3 * kC, kC, QKV, (long)kM * kC, nullptr,
            kC, kC, kC, kC);
        attn_score<<<dim3(kT / 32, kB * kH), 512, 0, stream>>>(QKV, QKV + (long)kM * kC, S);
        pv_kernel<<<dim3(16, 16), 512, 0, stream>>>(S, QKV + 2L * kM * kC, Y,
                                                    attm_base + (long)l * kH * kT * kT);
        gemm_bf16<2, 2, 4, 4, 4, 1><<<dim3(8, 32, 1), 256, 0, stream>>>(
            Y, 0L, WOT + (long)l * kC * kC, 0L, bo + l * kC, 0,
            nullptr, 0L, X, kC, kC, kC, kC);
        ln_kernel<<<kM, 256, 0, stream>>>(X, ln2w + l * kC, ln2b + l * kC, Hbuf, nullptr, 0);
        gemm_bf16<2, 2, 1, 2, 3, 0><<<dim3(2, 128, 1), 256, 0, stream>>>(
            Hbuf, 0L, W1T + (long)l * kFFP * kC, 0L, b1 + l * kFF, 0,
            F1, 0L, nullptr, kFFP, kC, kC, kC);
        gemm_bf16<2, 2, 4, 4, 4, 1><<<dim3(8, 32, 1), 256, 0, stream>>>(
            F1, 0L, W2T + (long)l * kC * kFFP, 0L, b2 + l * kC, 0,
            nullptr, 0L, X, kC, kFFP, kFFP, kFFP);
    }
    ln_kernel<<<kM, 256, 0, stream>>>(X, lnfw, lnfb, nullptr, XF, 1);
    pool_kernel<<<dim3(4, kB, 8), 256, 0, stream>>>(XF, pooled);
}